// Round 1
// 596.115 us; speedup vs baseline: 1.1317x; 1.1317x over previous
//
#include <hip/hip_runtime.h>
#include <hip/hip_bf16.h>

#define TOKENS 8192
#define IN_F   4096
#define OUT_F  4096

#define BM 256
#define BN 256
#define BK 64
#define NT (IN_F / BK)   // 64 K-tiles

typedef __attribute__((ext_vector_type(8))) short bf16x8;   // 8 bf16 = 4 VGPRs
typedef __attribute__((ext_vector_type(4))) float f32x4;

static __device__ __forceinline__ unsigned short f2bf(float f) {
    union { float f; unsigned int u; } v;
    v.f = f;
    unsigned int r = v.u + 0x7fffu + ((v.u >> 16) & 1u);   // RNE
    return (unsigned short)(r >> 16);
}

// rho ~ N(-4.6,1): exp(rho) ~ 0.01, fast log/exp error ~1e-6 rel << bf16 quantization
static __device__ __forceinline__ float softplus_fast(float x) {
    return __logf(1.0f + __expf(x));
}

#define XBLK 32768   // (TOKENS*IN_F/4)/256
#define WBLK 16384   // (OUT_F*IN_F/4)/256

// ---- fused prep: x->bf16, W = mu + softplus(rho)*eps -> bf16, bias fp32
__global__ __launch_bounds__(256) void prep_all_kernel(
        const float* __restrict__ x,
        const float* __restrict__ wmu,  const float* __restrict__ wrho,
        const float* __restrict__ epsw,
        const float* __restrict__ bmu,  const float* __restrict__ brho,
        const float* __restrict__ bepsb,
        __hip_bfloat16* __restrict__ xb, __hip_bfloat16* __restrict__ wb,
        float* __restrict__ bias) {
    const int b = blockIdx.x, t = threadIdx.x;
    if (b < XBLK) {
        const int i = b * 256 + t;
        float4 v = ((const float4*)x)[i];
        ushort4 o;
        o.x = f2bf(v.x); o.y = f2bf(v.y); o.z = f2bf(v.z); o.w = f2bf(v.w);
        ((ushort4*)xb)[i] = o;
    } else if (b < XBLK + WBLK) {
        const int i = (b - XBLK) * 256 + t;
        float4 m4 = ((const float4*)wmu)[i];
        float4 r4 = ((const float4*)wrho)[i];
        float4 e4 = ((const float4*)epsw)[i];
        ushort4 o;
        o.x = f2bf(m4.x + softplus_fast(r4.x) * e4.x);
        o.y = f2bf(m4.y + softplus_fast(r4.y) * e4.y);
        o.z = f2bf(m4.z + softplus_fast(r4.z) * e4.z);
        o.w = f2bf(m4.w + softplus_fast(r4.w) * e4.w);
        ((ushort4*)wb)[i] = o;
    } else {
        const int i = (b - XBLK - WBLK) * 256 + t;   // 0..1023
        float4 m4 = ((const float4*)bmu)[i];
        float4 r4 = ((const float4*)brho)[i];
        float4 e4 = ((const float4*)bepsb)[i];
        float4 o;
        o.x = m4.x + softplus_fast(r4.x) * e4.x;
        o.y = m4.y + softplus_fast(r4.y) * e4.y;
        o.z = m4.z + softplus_fast(r4.z) * e4.z;
        o.w = m4.w + softplus_fast(r4.w) * e4.w;
        ((float4*)bias)[i] = o;
    }
}

// ---- 256x256 tile, BK=64, 8 waves (2M x 4N), 8-phase schedule with counted vmcnt.
// LDS: per operand 2 slots x 2 K-halves x [256 rows][32 cols] bf16 (16 KiB each) = 128 KiB.
// Staging: global_load_lds width=16, linear LDS dest, swizzle applied by permuting the
// GLOBAL source chunk (rule #21); read side applies the same involution:
//   chunk' = chunk ^ ((row>>1)&3)  -> 2-way (free) bank aliasing on ds_read_b128.
// Schedule per K-tile t (phases P0..P3, 16 MFMA each):
//   P0: read A[m0-3]kh0 + B kh0 | stage Bkh0(t+1) | bar | lgkm0 | MFMA | bar
//   P1: read A[m4-7]kh0         | stage Akh1(t+1) | bar | lgkm0 | MFMA | vmcnt(6) bar
//   P2: read A[m0-3]kh1 + B kh1 | stage Bkh1(t+1) | bar | lgkm0 | MFMA | bar
//   P3: read A[m4-7]kh1         | stage Akh0(t+2) | bar | lgkm0 | MFMA | vmcnt(6) bar
// Each vmcnt(6) leaves exactly 3 half-tiles (6 loads) in flight and guarantees the
// halves consumed by the next two phases have landed (issue order: ...,Akh0(t+1)@(t-1,P3),
// Bkh0(t+1)@(t,P0), Akh1(t+1)@(t,P1), Bkh1(t+1)@(t,P2), Akh0(t+2)@(t,P3),...).
__global__ __launch_bounds__(512, 2) void gemm_256_kernel(
        const __hip_bfloat16* __restrict__ Xb,   // [TOKENS, IN_F]
        const __hip_bfloat16* __restrict__ Wb,   // [OUT_F, IN_F]
        const float* __restrict__ bias,          // [OUT_F]
        float* __restrict__ C) {                 // [TOKENS, OUT_F]
    __shared__ __align__(16) __hip_bfloat16 ldsA[2][2][BM * 32];
    __shared__ __align__(16) __hip_bfloat16 ldsB[2][2][BN * 32];

    const int tid  = threadIdx.x;
    const int lane = tid & 63;
    const int wave = tid >> 6;
    const int wm   = wave >> 2;   // 0..1 : wave's 128-row block
    const int wn   = wave & 3;    // 0..3 : wave's 64-col block
    const int fr   = lane & 15;
    const int quad = lane >> 4;

    const int rowBase = blockIdx.y * BM;   // token dim
    const int colBase = blockIdx.x * BN;   // out-feature dim

    // staging: thread t covers row = r*128 + t/4, 16B chunk (t&3), source pre-swizzled
    const int sRow = tid >> 2;
    const int sCol = ((tid & 3) ^ ((tid >> 3) & 3)) * 8;   // = chunk ^ ((row>>1)&3), in bf16
    const __hip_bfloat16* gA = Xb + (size_t)(rowBase + sRow) * IN_F + sCol;
    const __hip_bfloat16* gB = Wb + (size_t)(colBase + sRow) * IN_F + sCol;
    const int dstE = tid * 8;   // linear LDS dest (elems): wave-uniform base + lane*16B

    // read side: same involution -> per-lane constant chunk
    const int chunk = quad ^ ((fr >> 1) & 3);
    const int aOffE = wm * 4096 + fr * 32 + chunk * 8;   // + m*512 per 16-row frag
    const int bOffE = wn * 2048 + fr * 32 + chunk * 8;   // + n*512

    auto stageA = [&](int slot, int kh, int kt) {
        const __hip_bfloat16* src = gA + (size_t)kt * BK + (size_t)kh * 32;
        __hip_bfloat16* dst = &ldsA[slot][kh][dstE];
        __builtin_amdgcn_global_load_lds(
            (const __attribute__((address_space(1))) void*)src,
            (__attribute__((address_space(3))) void*)dst, 16, 0, 0);
        __builtin_amdgcn_global_load_lds(
            (const __attribute__((address_space(1))) void*)(src + (size_t)128 * IN_F),
            (__attribute__((address_space(3))) void*)(dst + 4096), 16, 0, 0);
    };
    auto stageB = [&](int slot, int kh, int kt) {
        const __hip_bfloat16* src = gB + (size_t)kt * BK + (size_t)kh * 32;
        __hip_bfloat16* dst = &ldsB[slot][kh][dstE];
        __builtin_amdgcn_global_load_lds(
            (const __attribute__((address_space(1))) void*)src,
            (__attribute__((address_space(3))) void*)dst, 16, 0, 0);
        __builtin_amdgcn_global_load_lds(
            (const __attribute__((address_space(1))) void*)(src + (size_t)128 * IN_F),
            (__attribute__((address_space(3))) void*)(dst + 4096), 16, 0, 0);
    };

    f32x4 acc[8][4];
#pragma unroll
    for (int m = 0; m < 8; ++m)
#pragma unroll
        for (int n = 0; n < 4; ++n) acc[m][n] = (f32x4){0.f, 0.f, 0.f, 0.f};

    // prologue: issue 5 half-tiles; wait until tile0 kh0 (A,B) landed (6 loads in flight)
    stageA(0, 0, 0);
    stageB(0, 0, 0);
    stageA(0, 1, 0);
    stageB(0, 1, 0);
    stageA(1, 0, 1);
    asm volatile("s_waitcnt vmcnt(6)" ::: "memory");
    __builtin_amdgcn_s_barrier();
    __builtin_amdgcn_sched_barrier(0);

    bf16x8 aR[4], bR[4];

    for (int t = 0; t < NT; ++t) {
        const int cs = t & 1, ns = cs ^ 1;
        const int t1 = (t + 1 < NT) ? (t + 1) : (NT - 1);   // clamp keeps vmcnt counts uniform
        const int t2 = (t + 2 < NT) ? (t + 2) : (NT - 1);
        const __hip_bfloat16* A0 = &ldsA[cs][0][0];
        const __hip_bfloat16* A1 = &ldsA[cs][1][0];
        const __hip_bfloat16* B0 = &ldsB[cs][0][0];
        const __hip_bfloat16* B1 = &ldsB[cs][1][0];

        // ---------- P0: (m0-3)x(n0-3), kh0
#pragma unroll
        for (int m = 0; m < 4; ++m) aR[m] = *(const bf16x8*)(A0 + aOffE + m * 512);
#pragma unroll
        for (int n = 0; n < 4; ++n) bR[n] = *(const bf16x8*)(B0 + bOffE + n * 512);
        stageB(ns, 0, t1);
        __builtin_amdgcn_s_barrier();
        asm volatile("s_waitcnt lgkmcnt(0)" ::: "memory");
        __builtin_amdgcn_s_setprio(1);
#pragma unroll
        for (int n = 0; n < 4; ++n)
#pragma unroll
            for (int m = 0; m < 4; ++m)
                acc[m][n] = __builtin_amdgcn_mfma_f32_16x16x32_bf16(aR[m], bR[n], acc[m][n], 0, 0, 0);
        __builtin_amdgcn_s_setprio(0);
        __builtin_amdgcn_s_barrier();

        // ---------- P1: (m4-7)x(n0-3), kh0 (reuse bR)
#pragma unroll
        for (int m = 0; m < 4; ++m) aR[m] = *(const bf16x8*)(A0 + aOffE + (m + 4) * 512);
        stageA(ns, 1, t1);
        __builtin_amdgcn_s_barrier();
        asm volatile("s_waitcnt lgkmcnt(0)" ::: "memory");
        __builtin_amdgcn_s_setprio(1);
#pragma unroll
        for (int n = 0; n < 4; ++n)
#pragma unroll
            for (int m = 0; m < 4; ++m)
                acc[m + 4][n] = __builtin_amdgcn_mfma_f32_16x16x32_bf16(aR[m], bR[n], acc[m + 4][n], 0, 0, 0);
        __builtin_amdgcn_s_setprio(0);
        asm volatile("s_waitcnt vmcnt(6)" ::: "memory");   // Akh1(t),Bkh1(t) landed
        __builtin_amdgcn_s_barrier();
        __builtin_amdgcn_sched_barrier(0);

        // ---------- P2: (m0-3)x(n0-3), kh1
#pragma unroll
        for (int m = 0; m < 4; ++m) aR[m] = *(const bf16x8*)(A1 + aOffE + m * 512);
#pragma unroll
        for (int n = 0; n < 4; ++n) bR[n] = *(const bf16x8*)(B1 + bOffE + n * 512);
        stageB(ns, 1, t1);
        __builtin_amdgcn_s_barrier();
        asm volatile("s_waitcnt lgkmcnt(0)" ::: "memory");
        __builtin_amdgcn_s_setprio(1);
#pragma unroll
        for (int n = 0; n < 4; ++n)
#pragma unroll
            for (int m = 0; m < 4; ++m)
                acc[m][n] = __builtin_amdgcn_mfma_f32_16x16x32_bf16(aR[m], bR[n], acc[m][n], 0, 0, 0);
        __builtin_amdgcn_s_setprio(0);
        __builtin_amdgcn_s_barrier();

        // ---------- P3: (m4-7)x(n0-3), kh1 (reuse bR); stage Akh0(t+2) into slot cs
#pragma unroll
        for (int m = 0; m < 4; ++m) aR[m] = *(const bf16x8*)(A1 + aOffE + (m + 4) * 512);
        stageA(cs, 0, t2);
        __builtin_amdgcn_s_barrier();
        asm volatile("s_waitcnt lgkmcnt(0)" ::: "memory");
        __builtin_amdgcn_s_setprio(1);
#pragma unroll
        for (int n = 0; n < 4; ++n)
#pragma unroll
            for (int m = 0; m < 4; ++m)
                acc[m + 4][n] = __builtin_amdgcn_mfma_f32_16x16x32_bf16(aR[m], bR[n], acc[m + 4][n], 0, 0, 0);
        __builtin_amdgcn_s_setprio(0);
        asm volatile("s_waitcnt vmcnt(6)" ::: "memory");   // Akh0(t+1),Bkh0(t+1) landed
        __builtin_amdgcn_s_barrier();
        __builtin_amdgcn_sched_barrier(0);
    }

    // epilogue: C/D layout col=lane&15, row=quad*4+reg
#pragma unroll
    for (int n = 0; n < 4; ++n) {
        const int col = colBase + wn * 64 + n * 16 + fr;
        const float bv = bias[col];
#pragma unroll
        for (int m = 0; m < 8; ++m) {
            const int row = rowBase + wm * 128 + m * 16 + quad * 4;
#pragma unroll
            for (int r = 0; r < 4; ++r)
                C[(size_t)(row + r) * OUT_F + col] = acc[m][n][r] + bv;
        }
    }
}

extern "C" void kernel_launch(void* const* d_in, const int* in_sizes, int n_in,
                              void* d_out, int out_size, void* d_ws, size_t ws_size,
                              hipStream_t stream) {
    const float* x    = (const float*)d_in[0];
    const float* wmu  = (const float*)d_in[1];
    const float* wrho = (const float*)d_in[2];
    const float* bmu  = (const float*)d_in[3];
    const float* brho = (const float*)d_in[4];
    const float* epsw = (const float*)d_in[5];
    const float* epsb = (const float*)d_in[6];
    float* out = (float*)d_out;

    // workspace: x_bf16 (67108864 B) | w_bf16 (33554432 B) | bias (16384 B)
    char* ws = (char*)d_ws;
    __hip_bfloat16* xb = (__hip_bfloat16*)ws;
    __hip_bfloat16* wb = (__hip_bfloat16*)(ws + (size_t)TOKENS * IN_F * 2);
    float* bias = (float*)(ws + (size_t)TOKENS * IN_F * 2 + (size_t)OUT_F * IN_F * 2);

    prep_all_kernel<<<XBLK + WBLK + 4, 256, 0, stream>>>(
        x, wmu, wrho, epsw, bmu, brho, epsb, xb, wb, bias);

    dim3 grid(OUT_F / BN, TOKENS / BM);   // (16, 32)
    gemm_256_kernel<<<grid, 512, 0, stream>>>(xb, wb, bias, out);
}